// Round 2
// baseline (249.928 us; speedup 1.0000x reference)
//
#include <hip/hip_runtime.h>

// MultiHeadedAttention: B=2, S=2048, D=1024, H=16, DH=64. fp32 in/out.
// R12: attn occupancy + L2 locality (was 53us, VALUBusy 57%, MfmaUtil 26%,
// ~40% dual-pipe-idle => correlated barrier stalls at 2 blocks/CU):
//  - 64 q-rows/block (4 waves, 256 thr), grid 1024 -> 4 blocks/CU: four
//    independent barrier domains per CU instead of two.
//  - XCD-grouped mapping: bh group = blockIdx&7 (the XCD round-robin digit),
//    so each XCD's 128 resident blocks share 4 bh's KV (2MB, L2-resident).
//  - mask word pre-shifted by quad*4 once per 32-key word.
// Math byte-identical to R11. gemm_qkv / gemm_final / converts unchanged.
#define B_ 2
#define S_ 2048
#define D_ 1024
#define H_ 16
#define DH_ 64

typedef float f32x4 __attribute__((ext_vector_type(4)));
typedef short s16x8 __attribute__((ext_vector_type(8)));
typedef __bf16 bf16x8 __attribute__((ext_vector_type(8)));
typedef unsigned int uint;

// ---- MFMA wrapper: tolerate either builtin signature (short8 or bf16x8) ----
template <typename T>
static __device__ auto mfma_sel(T a, T b, f32x4 c, int)
    -> decltype(__builtin_amdgcn_mfma_f32_16x16x32_bf16(a, b, c, 0, 0, 0)) {
  return __builtin_amdgcn_mfma_f32_16x16x32_bf16(a, b, c, 0, 0, 0);
}
template <typename T>
static __device__ f32x4 mfma_sel(T a, T b, f32x4 c, long) {
  return __builtin_amdgcn_mfma_f32_16x16x32_bf16(
      __builtin_bit_cast(bf16x8, a), __builtin_bit_cast(bf16x8, b), c, 0, 0, 0);
}
static __device__ __forceinline__ f32x4 mfma_bf16(s16x8 a, s16x8 b, f32x4 c) {
  return mfma_sel(a, b, c, 0);
}

static __device__ __forceinline__ short f2bf(float f) {
  unsigned u = __float_as_uint(f);
  u += 0x7fffu + ((u >> 16) & 1u);
  return (short)(u >> 16);
}

// hardware RNE convert (v_cvt_pk_bf16_f32) -- bit-identical to f2bf for
// non-NaN inputs, ~1 instruction instead of ~5.
static __device__ __forceinline__ short f2bf_rn(float f) {
  return __builtin_bit_cast(short, (__bf16)f);
}

// ---- async 16B global -> LDS (per-lane GLOBAL addr ok; LDS side = base+lane*16)
static __device__ __forceinline__ void async16(const short* g, short* l) {
  __builtin_amdgcn_global_load_lds(
      (const __attribute__((address_space(1))) unsigned int*)g,
      (__attribute__((address_space(3))) unsigned int*)l, 16, 0, 0);
}

// ---- mask dtype probe: 0 = byte-bool, 1 = int32 0/1, 2 = fp32 0.0/1.0 ----
__global__ void detect_mask_kernel(const uint* __restrict__ m,
                                   int* __restrict__ flag) {
  int lane = threadIdx.x;
  bool gt1 = false, notf = false;
  for (int i = 0; i < 16; ++i) {
    uint v = m[lane * 16 + i];
    if (v > 1u) gt1 = true;
    if (v != 0u && v != 0x3F800000u) notf = true;
  }
  unsigned long long b1 = __ballot(gt1);
  unsigned long long b2 = __ballot(notf);
  if (lane == 0) {
    int f;
    if (b1 == 0ull) f = 1;
    else if (b2 == 0ull) f = 2;
    else f = 0;
    *flag = f;
  }
}

// ---- mask -> bitmask. bmT[b][kt][q] bit i = (mask[b][q][kt*32+i] != 0) ----
__global__ __launch_bounds__(256) void build_bitmask_kernel(
    const void* __restrict__ mask, const int* __restrict__ flag,
    uint* __restrict__ bmT) {
  int w = blockIdx.x * 256 + threadIdx.x;
  int b = w >> 17;
  int rem = w & 131071;
  int q = rem >> 6;
  int kt = rem & 63;
  int mty = *flag;
  uint bits = 0;
  if (mty == 0) {
    const uint* p = (const uint*)((const unsigned char*)mask +
                                  ((size_t)b * S_ + q) * S_ + (size_t)kt * 32);
#pragma unroll
    for (int i = 0; i < 8; ++i) {
      uint v = p[i];
#pragma unroll
      for (int j = 0; j < 4; ++j)
        if ((v >> (8 * j)) & 0xffu) bits |= 1u << (i * 4 + j);
    }
  } else {
    const uint* p = (const uint*)mask + ((size_t)b * S_ + q) * S_ + kt * 32;
#pragma unroll
    for (int i = 0; i < 32; ++i)
      if (p[i]) bits |= 1u << i;
  }
  bmT[((size_t)b * (S_ / 32) + kt) * S_ + q] = bits;
}

// ---- fp32 -> bf16 convert into FRAGMENT-ORDER layout (query + Wq/Wk/Wv) ----
__global__ __launch_bounds__(256) void convert_kernel(
    const float* __restrict__ q, const float* __restrict__ wq,
    const float* __restrict__ wk, const float* __restrict__ wv,
    short* __restrict__ qbf, short* __restrict__ wqkv) {
  int bid = blockIdx.x;
  int t = threadIdx.x;
  const float* src;
  short* dst;
  int rowbase, seg;
  if (bid < 2048)      { src = q;  dst = qbf;  rowbase = bid * 2;          seg = -1; }
  else if (bid < 2560) { src = wq; dst = wqkv; rowbase = (bid - 2048) * 2; seg = 0; }
  else if (bid < 3072) { src = wk; dst = wqkv; rowbase = (bid - 2560) * 2; seg = 1; }
  else                 { src = wv; dst = wqkv; rowbase = (bid - 3072) * 2; seg = 2; }
  int rl = rowbase + (t >> 7);
  int k = (t & 127) * 8;
  const float* s8 = src + (size_t)rl * 1024 + k;
  f32x4 a = *(const f32x4*)s8;
  f32x4 b = *(const f32x4*)(s8 + 4);
  s16x8 r;
  r[0] = f2bf(a[0]); r[1] = f2bf(a[1]); r[2] = f2bf(a[2]); r[3] = f2bf(a[3]);
  r[4] = f2bf(b[0]); r[5] = f2bf(b[1]); r[6] = f2bf(b[2]); r[7] = f2bf(b[3]);
  int grow = (seg < 0) ? rl : (seg * 1024 + rl);
  size_t chunk = ((size_t)(grow >> 4) * 32 + (k >> 5)) * 64 +
                 ((k >> 3) & 3) * 16 + (grow & 15);
  *(s16x8*)(dst + chunk * 8) = r;
}

// ---- fp32 -> bf16 row-major convert for Wo (runs AFTER attn, into q_ws) ----
__global__ __launch_bounds__(256) void convert_wo_kernel(
    const float* __restrict__ wo, short* __restrict__ wob) {
  size_t i = ((size_t)blockIdx.x * 256 + threadIdx.x) * 8;
  f32x4 a = *(const f32x4*)(wo + i);
  f32x4 b = *(const f32x4*)(wo + i + 4);
  s16x8 r;
  r[0] = f2bf(a[0]); r[1] = f2bf(a[1]); r[2] = f2bf(a[2]); r[3] = f2bf(a[3]);
  r[4] = f2bf(b[0]); r[5] = f2bf(b[1]); r[6] = f2bf(b[2]); r[7] = f2bf(b[3]);
  *(s16x8*)(wob + i) = r;
}

// ---- fused QKV GEMM, staged: C[4096,3072] = qbf @ wqkv^T ------------------
__global__ __launch_bounds__(256) void gemm_qkv_kernel(
    const short* __restrict__ A, const short* __restrict__ Bt,
    const float* __restrict__ bq, const float* __restrict__ bk,
    const float* __restrict__ bv, short* __restrict__ q_ws,
    short* __restrict__ KF, short* __restrict__ VF) {
  __shared__ short lds[8192];
  const int tid = threadIdx.x;
  const int lane = tid & 63;
  const int wave = tid >> 6;
  const int l16 = lane & 15;
  const int quad = lane >> 4;
  const int mb0 = blockIdx.x * 8;
  const int nb0 = blockIdx.y * 8;
  const int m0 = blockIdx.x * 128 + (wave >> 1) * 64;
  const int n0 = blockIdx.y * 128 + (wave & 1) * 64;
  const int g = tid >> 6, c = tid & 63;

  f32x4 acc[4][4];
#pragma unroll
  for (int i = 0; i < 4; ++i)
#pragma unroll
    for (int j = 0; j < 4; ++j) acc[i][j] = (f32x4){0.f, 0.f, 0.f, 0.f};

  for (int kb = 0; kb < 32; ++kb) {
    async16(A + (((size_t)(mb0 + g) * 32 + kb) * 64 + c) * 8, lds + tid * 8);
    async16(A + (((size_t)(mb0 + g + 4) * 32 + kb) * 64 + c) * 8,
            lds + 2048 + tid * 8);
    async16(Bt + (((size_t)(nb0 + g) * 32 + kb) * 64 + c) * 8,
            lds + 4096 + tid * 8);
    async16(Bt + (((size_t)(nb0 + g + 4) * 32 + kb) * 64 + c) * 8,
            lds + 6144 + tid * 8);
    __syncthreads();
    s16x8 a[4], b[4];
#pragma unroll
    for (int i = 0; i < 4; ++i)
      a[i] = *(const s16x8*)(lds + (((wave >> 1) * 4 + i) * 64 + lane) * 8);
#pragma unroll
    for (int j = 0; j < 4; ++j)
      b[j] = *(const s16x8*)(lds + 4096 + (((wave & 1) * 4 + j) * 64 + lane) * 8);
#pragma unroll
    for (int i = 0; i < 4; ++i)
#pragma unroll
      for (int j = 0; j < 4; ++j) acc[i][j] = mfma_bf16(a[i], b[j], acc[i][j]);
    __syncthreads();
  }

#pragma unroll
  for (int i = 0; i < 4; ++i) {
#pragma unroll
    for (int j = 0; j < 4; ++j) {
#pragma unroll
      for (int r = 0; r < 4; ++r) {
        int m = m0 + i * 16 + quad * 4 + r;
        int n = n0 + j * 16 + l16;
        int seg = n >> 10, nl = n & 1023;
        float bias = (seg == 0) ? bq[nl] : ((seg == 1) ? bk[nl] : bv[nl]);
        float v = acc[i][j][r] + bias;
        // Q scale: 1/sqrt(DH) * log2(e), so attn can use raw exp2.
        if (seg == 0) v *= 0.18033688011112042f;
        int bb = m >> 11, s = m & (S_ - 1);
        int hh = nl >> 6, dh = nl & 63;
        int bh = bb * H_ + hh;
        short bv16 = f2bf(v);
        if (seg == 0) {
          q_ws[((size_t)bh * S_ + s) * DH_ + dh] = bv16;
        } else if (seg == 1) {
          int kt = s >> 5, r5 = s & 31;
          int kkb = r5 >> 4, kl16 = r5 & 15;
          int kf = dh >> 5, qd = (dh >> 3) & 3, e = dh & 7;
          KF[(size_t)bh * 131072 +
             ((size_t)kt * 256 + (kkb * 2 + kf) * 64 + qd * 16 + kl16) * 8 + e] = bv16;
        } else {
          int kt = s >> 5, ko = s & 31;
          int hi = ko >> 4, qd = (ko >> 2) & 3, j4 = ko & 3;
          int nb = dh >> 4, vl16 = dh & 15, e = hi * 4 + j4;
          VF[(size_t)bh * 131072 +
             ((size_t)kt * 256 + nb * 64 + qd * 16 + vl16) * 8 + e] = bv16;
        }
      }
    }
  }
}

// ---- attention: 1024 blocks x 4 waves (64 q-rows/block), BK=64, dbuf ------
// Block mapping: XCD digit (bid&7) picks the bh group so each XCD's resident
// blocks share 4 bh's KV (2MB) in its 4MB L2.
__global__ void attn_kernel(
    const short* __restrict__ Q, const short* __restrict__ KF,
    const short* __restrict__ VF, const uint* __restrict__ bmT,
    short* __restrict__ ctx_out) {
  // two buffers of (K 64x64 | V 64x64): buf c at lds + c*8192 shorts (32KB)
  __shared__ short lds[16384];
  const int tid = threadIdx.x;           // [0,256)
  const int lane = tid & 63;
  const int wave = tid >> 6;             // [0,4)
  const int l16 = lane & 15;
  const int quad = lane >> 4;
  const int xcd = blockIdx.x & 7;        // hw round-robin digit
  const int slot = blockIdx.x >> 3;      // [0,128)
  const int bh = xcd * 4 + (slot >> 5);  // 32 bh, grouped 4-per-XCD
  const int qt64 = slot & 31;            // [0,32)
  const int b = bh >> 4;
  const int h = bh & 15;
  const int qbase = qt64 * 64 + wave * 16;
  const int qcol = qbase + l16;

  const short* Qh = Q + (size_t)bh * S_ * DH_;
  const short* KFb = KF + (size_t)bh * 131072;
  const short* VFb = VF + (size_t)bh * 131072;
  const uint* bmb = bmT + (size_t)b * (S_ / 32) * S_;

  s16x8 qf[2];
#pragma unroll
  for (int kf = 0; kf < 2; ++kf)
    qf[kf] = *(const s16x8*)(Qh + (size_t)qcol * DH_ + kf * 32 + quad * 8);

  f32x4 ctx[4];
#pragma unroll
  for (int nb = 0; nb < 4; ++nb) ctx[nb] = (f32x4){0.f, 0.f, 0.f, 0.f};
  float ls = 0.f;

  // prologue: stage tile 0 into buffer 0 (16KB by 256 thr = 4 async16 each)
  async16(KFb + tid * 8, lds + tid * 8);
  async16(KFb + 2048 + tid * 8, lds + 2048 + tid * 8);
  async16(VFb + tid * 8, lds + 4096 + tid * 8);
  async16(VFb + 2048 + tid * 8, lds + 6144 + tid * 8);
  uint w0 = bmb[qcol];
  uint w1 = bmb[(size_t)S_ + qcol];
  __syncthreads();  // drains vmcnt(0): buffer 0 ready

  for (int kt2 = 0; kt2 < S_ / 64; ++kt2) {
    // issue next tile's stage + mask prefetch BEFORE computing current tile:
    // HBM/L2 latency hides under the 16 MFMA + softmax below.
    uint wn0 = 0, wn1 = 0;
    if (kt2 < S_ / 64 - 1) {
      const int st = ((kt2 & 1) ^ 1) << 13;  // other buffer, in shorts
      const short* kg = KFb + (size_t)(kt2 + 1) * 4096;
      const short* vg = VFb + (size_t)(kt2 + 1) * 4096;
      async16(kg + tid * 8, lds + st + tid * 8);
      async16(kg + 2048 + tid * 8, lds + st + 2048 + tid * 8);
      async16(vg + tid * 8, lds + st + 4096 + tid * 8);
      async16(vg + 2048 + tid * 8, lds + st + 6144 + tid * 8);
      wn0 = bmb[(size_t)(2 * kt2 + 2) * S_ + qcol];
      wn1 = bmb[(size_t)(2 * kt2 + 3) * S_ + qcol];
    }
    const short* kls = lds + ((kt2 & 1) << 13);
    const short* vls = kls + 4096;
    // pre-shift mask words by quad*4: bit for (kb,r) is at kb*16+r (const)
    const uint wcur[2] = {w0 >> (quad * 4), w1 >> (quad * 4)};

#pragma unroll
    for (int kbt = 0; kbt < 2; ++kbt) {
      s16x8 ka[2][2];
#pragma unroll
      for (int kb = 0; kb < 2; ++kb)
#pragma unroll
        for (int kf = 0; kf < 2; ++kf)
          ka[kb][kf] =
              *(const s16x8*)(kls + kbt * 2048 + ((kb * 2 + kf) * 64 + lane) * 8);

      // scores^T: C row = key(quad*4+r), col = q(l16)
      f32x4 sc[2];
#pragma unroll
      for (int kb = 0; kb < 2; ++kb) {
        f32x4 t = mfma_bf16(ka[kb][0], qf[0], (f32x4){0.f, 0.f, 0.f, 0.f});
        sc[kb] = mfma_bf16(ka[kb][1], qf[1], t);
      }

      // exp2 (scale pre-folded) + mask + hw-cvt pack to PV A-operand
      s16x8 pa;
      float sum = 0.f;
#pragma unroll
      for (int kb = 0; kb < 2; ++kb)
#pragma unroll
        for (int r = 0; r < 4; ++r) {
          int bit = (wcur[kbt] >> (kb * 16 + r)) & 1;
          float p = bit ? 0.f : __builtin_amdgcn_exp2f(sc[kb][r]);
          sum += p;
          pa[kb * 4 + r] = f2bf_rn(p);
        }
      ls += sum;

#pragma unroll
      for (int nb = 0; nb < 4; ++nb) {
        s16x8 vb = *(const s16x8*)(vls + kbt * 2048 + (nb * 64 + lane) * 8);
        ctx[nb] = mfma_bf16(pa, vb, ctx[nb]);
      }
    }
    __syncthreads();  // next buffer staged (vmcnt drain) + current reads done
    w0 = wn0;
    w1 = wn1;
  }

  // reduce l over the 4 quads: every lane ends with row l16's total
  ls += __shfl_xor(ls, 16);
  ls += __shfl_xor(ls, 32);

  // epilogue: ctx C-layout row = q(quad*4+r), col = dh(l16); row-major out
#pragma unroll
  for (int r = 0; r < 4; ++r) {
    float lr = __shfl(ls, quad * 4 + r);
    float inv = 1.f / lr;
    int srow = qbase + quad * 4 + r;
#pragma unroll
    for (int nb = 0; nb < 4; ++nb) {
      int col = h * DH_ + nb * 16 + l16;
      ctx_out[(size_t)(b * S_ + srow) * D_ + col] = f2bf(ctx[nb][r] * inv);
    }
  }
}

// ---- final GEMM, staged: out[4096,1024] fp32 = ctx_bf16 @ Wo_bf16^T + bo ---
__global__ __launch_bounds__(256) void gemm_final_kernel(
    const short* __restrict__ A, const short* __restrict__ Bt,
    const float* __restrict__ bias, float* __restrict__ out) {
  __shared__ short lds[8192];
  const int tid = threadIdx.x;
  const int lane = tid & 63;
  const int wave = tid >> 6;
  const int l16 = lane & 15;
  const int quad = lane >> 4;
  const int m0 = blockIdx.x * 128;
  const int n0 = blockIdx.y * 128;
  const int g = tid >> 6, c = tid & 63;
  const int r15 = c & 15, qd = c >> 4;

  f32x4 acc[4][4];
#pragma unroll
  for (int i = 0; i < 4; ++i)
#pragma unroll
    for (int j = 0; j < 4; ++j) acc[i][j] = (f32x4){0.f, 0.f, 0.f, 0.f};

  for (int k0 = 0; k0 < 1024; k0 += 32) {
    async16(A + (size_t)(m0 + g * 16 + r15) * 1024 + k0 + qd * 8, lds + tid * 8);
    async16(A + (size_t)(m0 + (g + 4) * 16 + r15) * 1024 + k0 + qd * 8,
            lds + 2048 + tid * 8);
    async16(Bt + (size_t)(n0 + g * 16 + r15) * 1024 + k0 + qd * 8,
            lds + 4096 + tid * 8);
    async16(Bt + (size_t)(n0 + (g + 4) * 16 + r15) * 1024 + k0 + qd * 8,
            lds + 6144 + tid * 8);
    __syncthreads();
    s16x8 a[4], b[4];
#pragma unroll
    for (int i = 0; i < 4; ++i)
      a[i] = *(const s16x8*)(lds + (((wave >> 1) * 4 + i) * 64 + lane) * 8);
#pragma unroll
    for (int j = 0; j < 4; ++j)
      b[j] = *(const s16x8*)(lds + 4096 + (((wave & 1) * 4 + j) * 64 + lane) * 8);
#pragma unroll
    for (int i = 0; i < 4; ++i)
#pragma unroll
      for (int j = 0; j < 4; ++j) acc[i][j] = mfma_bf16(a[i], b[j], acc[i][j]);
    __syncthreads();
  }

  const int mw = m0 + (wave >> 1) * 64;
  const int nw = n0 + (wave & 1) * 64;
#pragma unroll
  for (int i = 0; i < 4; ++i)
#pragma unroll
    for (int j = 0; j < 4; ++j)
#pragma unroll
      for (int r = 0; r < 4; ++r) {
        int m = mw + i * 16 + quad * 4 + r;
        int n = nw + j * 16 + l16;
        out[(size_t)m * 1024 + n] = acc[i][j][r] + bias[n];
      }
}

extern "C" void kernel_launch(void* const* d_in, const int* in_sizes, int n_in,
                              void* d_out, int out_size, void* d_ws,
                              size_t ws_size, hipStream_t stream) {
  const float* query = (const float*)d_in[0];
  const void* mask = d_in[1];
  const float* Wq = (const float*)d_in[2];
  const float* bq = (const float*)d_in[3];
  const float* Wk = (const float*)d_in[4];
  const float* bk = (const float*)d_in[5];
  const float* Wv = (const float*)d_in[6];
  const float* bv = (const float*)d_in[7];
  const float* Wo = (const float*)d_in[8];
  const float* bo = (const float*)d_in[9];

  const size_t NE = (size_t)B_ * S_ * D_;  // 4194304
  short* ws_s = (short*)d_ws;
  short* q_ws = ws_s;             // [B,H,S,DH] bf16 row-major (8 MB)
  short* KF = ws_s + NE;          // K fragment-order (8 MB)
  short* VF = ws_s + 2 * NE;      // V fragment-order, PV-permuted (8 MB)
  short* ctx_ws = ws_s + 3 * NE;  // [B,S,D] bf16 row-major (8 MB)
  short* wo_bf = ws_s;            // Wo bf16 (2 MB) -- aliases q_ws, written
                                  // only after attn (q_ws dead then)
  // scratch inside d_out (all dead before the final GEMM runs):
  short* qbf = (short*)d_out;          // [0:8M)  query bf16, fragment order
  short* wqkv = qbf + NE;              // [8:14M) Wq|Wk|Wv bf16, fragment order
  uint* bmT = (uint*)(wqkv + 3145728); // [14:15M) bitmask
  int* flag = (int*)(bmT + 262144);

  detect_mask_kernel<<<1, 64, 0, stream>>>((const uint*)mask, flag);
  build_bitmask_kernel<<<1024, 256, 0, stream>>>(mask, flag, bmT);
  convert_kernel<<<3584, 256, 0, stream>>>(query, Wq, Wk, Wv, qbf, wqkv);

  gemm_qkv_kernel<<<dim3(32, 24), 256, 0, stream>>>(qbf, wqkv, bq, bk, bv,
                                                    q_ws, KF, VF);

  attn_kernel<<<1024, 256, 0, stream>>>(q_ws, KF, VF, bmT, ctx_ws);

  convert_wo_kernel<<<512, 256, 0, stream>>>(Wo, wo_bf);

  gemm_final_kernel<<<dim3(32, 8), 256, 0, stream>>>(ctx_ws, wo_bf, bo,
                                                     (float*)d_out);
}

// Round 3
// 237.094 us; speedup vs baseline: 1.0541x; 1.0541x over previous
//
#include <hip/hip_runtime.h>

// MultiHeadedAttention: B=2, S=2048, D=1024, H=16, DH=64. fp32 in/out.
// R13: halve attn LDS-read traffic (R11 analysis: 2.1GB LDS reads = ~27us of
// the 53us kernel; R12's 64q blocks doubled staging -> reverted):
//  - back to 128 q/block, 512 thr, 8 waves, grid 512 (R11 staging economics)
//  - KEEP R12's XCD-grouped mapping (FETCH 70->14MB confirmed)
//  - NEW: wave = 32 q-rows x fixed 32-key half (kbt=wave&1). Per kt2 a wave
//    reads 8KB (K-half+V-half) for 32q x 32k instead of 16KB for 16q x 64k:
//    per-q LDS reads halved; V reads shared across the 2 Q-groups.
//  - end: one elementwise same-lane pair-reduction (ctx+ls) across key-halves
//    via LDS (once per kernel, ~64KB traffic).
// gemm_qkv / gemm_final / converts unchanged.
#define B_ 2
#define S_ 2048
#define D_ 1024
#define H_ 16
#define DH_ 64

typedef float f32x4 __attribute__((ext_vector_type(4)));
typedef short s16x8 __attribute__((ext_vector_type(8)));
typedef __bf16 bf16x8 __attribute__((ext_vector_type(8)));
typedef unsigned int uint;

// ---- MFMA wrapper: tolerate either builtin signature (short8 or bf16x8) ----
template <typename T>
static __device__ auto mfma_sel(T a, T b, f32x4 c, int)
    -> decltype(__builtin_amdgcn_mfma_f32_16x16x32_bf16(a, b, c, 0, 0, 0)) {
  return __builtin_amdgcn_mfma_f32_16x16x32_bf16(a, b, c, 0, 0, 0);
}
template <typename T>
static __device__ f32x4 mfma_sel(T a, T b, f32x4 c, long) {
  return __builtin_amdgcn_mfma_f32_16x16x32_bf16(
      __builtin_bit_cast(bf16x8, a), __builtin_bit_cast(bf16x8, b), c, 0, 0, 0);
}
static __device__ __forceinline__ f32x4 mfma_bf16(s16x8 a, s16x8 b, f32x4 c) {
  return mfma_sel(a, b, c, 0);
}

static __device__ __forceinline__ short f2bf(float f) {
  unsigned u = __float_as_uint(f);
  u += 0x7fffu + ((u >> 16) & 1u);
  return (short)(u >> 16);
}

// hardware RNE convert (v_cvt_pk_bf16_f32) -- bit-identical to f2bf for
// non-NaN inputs.
static __device__ __forceinline__ short f2bf_rn(float f) {
  return __builtin_bit_cast(short, (__bf16)f);
}

// ---- async 16B global -> LDS (per-lane GLOBAL addr ok; LDS side = base+lane*16)
static __device__ __forceinline__ void async16(const short* g, short* l) {
  __builtin_amdgcn_global_load_lds(
      (const __attribute__((address_space(1))) unsigned int*)g,
      (__attribute__((address_space(3))) unsigned int*)l, 16, 0, 0);
}

// ---- mask dtype probe: 0 = byte-bool, 1 = int32 0/1, 2 = fp32 0.0/1.0 ----
__global__ void detect_mask_kernel(const uint* __restrict__ m,
                                   int* __restrict__ flag) {
  int lane = threadIdx.x;
  bool gt1 = false, notf = false;
  for (int i = 0; i < 16; ++i) {
    uint v = m[lane * 16 + i];
    if (v > 1u) gt1 = true;
    if (v != 0u && v != 0x3F800000u) notf = true;
  }
  unsigned long long b1 = __ballot(gt1);
  unsigned long long b2 = __ballot(notf);
  if (lane == 0) {
    int f;
    if (b1 == 0ull) f = 1;
    else if (b2 == 0ull) f = 2;
    else f = 0;
    *flag = f;
  }
}

// ---- mask -> bitmask. bmT[b][kt][q] bit i = (mask[b][q][kt*32+i] != 0) ----
__global__ __launch_bounds__(256) void build_bitmask_kernel(
    const void* __restrict__ mask, const int* __restrict__ flag,
    uint* __restrict__ bmT) {
  int w = blockIdx.x * 256 + threadIdx.x;
  int b = w >> 17;
  int rem = w & 131071;
  int q = rem >> 6;
  int kt = rem & 63;
  int mty = *flag;
  uint bits = 0;
  if (mty == 0) {
    const uint* p = (const uint*)((const unsigned char*)mask +
                                  ((size_t)b * S_ + q) * S_ + (size_t)kt * 32);
#pragma unroll
    for (int i = 0; i < 8; ++i) {
      uint v = p[i];
#pragma unroll
      for (int j = 0; j < 4; ++j)
        if ((v >> (8 * j)) & 0xffu) bits |= 1u << (i * 4 + j);
    }
  } else {
    const uint* p = (const uint*)mask + ((size_t)b * S_ + q) * S_ + kt * 32;
#pragma unroll
    for (int i = 0; i < 32; ++i)
      if (p[i]) bits |= 1u << i;
  }
  bmT[((size_t)b * (S_ / 32) + kt) * S_ + q] = bits;
}

// ---- fp32 -> bf16 convert into FRAGMENT-ORDER layout (query + Wq/Wk/Wv) ----
__global__ __launch_bounds__(256) void convert_kernel(
    const float* __restrict__ q, const float* __restrict__ wq,
    const float* __restrict__ wk, const float* __restrict__ wv,
    short* __restrict__ qbf, short* __restrict__ wqkv) {
  int bid = blockIdx.x;
  int t = threadIdx.x;
  const float* src;
  short* dst;
  int rowbase, seg;
  if (bid < 2048)      { src = q;  dst = qbf;  rowbase = bid * 2;          seg = -1; }
  else if (bid < 2560) { src = wq; dst = wqkv; rowbase = (bid - 2048) * 2; seg = 0; }
  else if (bid < 3072) { src = wk; dst = wqkv; rowbase = (bid - 2560) * 2; seg = 1; }
  else                 { src = wv; dst = wqkv; rowbase = (bid - 3072) * 2; seg = 2; }
  int rl = rowbase + (t >> 7);
  int k = (t & 127) * 8;
  const float* s8 = src + (size_t)rl * 1024 + k;
  f32x4 a = *(const f32x4*)s8;
  f32x4 b = *(const f32x4*)(s8 + 4);
  s16x8 r;
  r[0] = f2bf(a[0]); r[1] = f2bf(a[1]); r[2] = f2bf(a[2]); r[3] = f2bf(a[3]);
  r[4] = f2bf(b[0]); r[5] = f2bf(b[1]); r[6] = f2bf(b[2]); r[7] = f2bf(b[3]);
  int grow = (seg < 0) ? rl : (seg * 1024 + rl);
  size_t chunk = ((size_t)(grow >> 4) * 32 + (k >> 5)) * 64 +
                 ((k >> 3) & 3) * 16 + (grow & 15);
  *(s16x8*)(dst + chunk * 8) = r;
}

// ---- fp32 -> bf16 row-major convert for Wo (runs AFTER attn, into q_ws) ----
__global__ __launch_bounds__(256) void convert_wo_kernel(
    const float* __restrict__ wo, short* __restrict__ wob) {
  size_t i = ((size_t)blockIdx.x * 256 + threadIdx.x) * 8;
  f32x4 a = *(const f32x4*)(wo + i);
  f32x4 b = *(const f32x4*)(wo + i + 4);
  s16x8 r;
  r[0] = f2bf(a[0]); r[1] = f2bf(a[1]); r[2] = f2bf(a[2]); r[3] = f2bf(a[3]);
  r[4] = f2bf(b[0]); r[5] = f2bf(b[1]); r[6] = f2bf(b[2]); r[7] = f2bf(b[3]);
  *(s16x8*)(wob + i) = r;
}

// ---- fused QKV GEMM, staged: C[4096,3072] = qbf @ wqkv^T ------------------
__global__ __launch_bounds__(256) void gemm_qkv_kernel(
    const short* __restrict__ A, const short* __restrict__ Bt,
    const float* __restrict__ bq, const float* __restrict__ bk,
    const float* __restrict__ bv, short* __restrict__ q_ws,
    short* __restrict__ KF, short* __restrict__ VF) {
  __shared__ short lds[8192];
  const int tid = threadIdx.x;
  const int lane = tid & 63;
  const int wave = tid >> 6;
  const int l16 = lane & 15;
  const int quad = lane >> 4;
  const int mb0 = blockIdx.x * 8;
  const int nb0 = blockIdx.y * 8;
  const int m0 = blockIdx.x * 128 + (wave >> 1) * 64;
  const int n0 = blockIdx.y * 128 + (wave & 1) * 64;
  const int g = tid >> 6, c = tid & 63;

  f32x4 acc[4][4];
#pragma unroll
  for (int i = 0; i < 4; ++i)
#pragma unroll
    for (int j = 0; j < 4; ++j) acc[i][j] = (f32x4){0.f, 0.f, 0.f, 0.f};

  for (int kb = 0; kb < 32; ++kb) {
    async16(A + (((size_t)(mb0 + g) * 32 + kb) * 64 + c) * 8, lds + tid * 8);
    async16(A + (((size_t)(mb0 + g + 4) * 32 + kb) * 64 + c) * 8,
            lds + 2048 + tid * 8);
    async16(Bt + (((size_t)(nb0 + g) * 32 + kb) * 64 + c) * 8,
            lds + 4096 + tid * 8);
    async16(Bt + (((size_t)(nb0 + g + 4) * 32 + kb) * 64 + c) * 8,
            lds + 6144 + tid * 8);
    __syncthreads();
    s16x8 a[4], b[4];
#pragma unroll
    for (int i = 0; i < 4; ++i)
      a[i] = *(const s16x8*)(lds + (((wave >> 1) * 4 + i) * 64 + lane) * 8);
#pragma unroll
    for (int j = 0; j < 4; ++j)
      b[j] = *(const s16x8*)(lds + 4096 + (((wave & 1) * 4 + j) * 64 + lane) * 8);
#pragma unroll
    for (int i = 0; i < 4; ++i)
#pragma unroll
      for (int j = 0; j < 4; ++j) acc[i][j] = mfma_bf16(a[i], b[j], acc[i][j]);
    __syncthreads();
  }

#pragma unroll
  for (int i = 0; i < 4; ++i) {
#pragma unroll
    for (int j = 0; j < 4; ++j) {
#pragma unroll
      for (int r = 0; r < 4; ++r) {
        int m = m0 + i * 16 + quad * 4 + r;
        int n = n0 + j * 16 + l16;
        int seg = n >> 10, nl = n & 1023;
        float bias = (seg == 0) ? bq[nl] : ((seg == 1) ? bk[nl] : bv[nl]);
        float v = acc[i][j][r] + bias;
        // Q scale: 1/sqrt(DH) * log2(e), so attn can use raw exp2.
        if (seg == 0) v *= 0.18033688011112042f;
        int bb = m >> 11, s = m & (S_ - 1);
        int hh = nl >> 6, dh = nl & 63;
        int bh = bb * H_ + hh;
        short bv16 = f2bf(v);
        if (seg == 0) {
          q_ws[((size_t)bh * S_ + s) * DH_ + dh] = bv16;
        } else if (seg == 1) {
          int kt = s >> 5, r5 = s & 31;
          int kkb = r5 >> 4, kl16 = r5 & 15;
          int kf = dh >> 5, qd = (dh >> 3) & 3, e = dh & 7;
          KF[(size_t)bh * 131072 +
             ((size_t)kt * 256 + (kkb * 2 + kf) * 64 + qd * 16 + kl16) * 8 + e] = bv16;
        } else {
          int kt = s >> 5, ko = s & 31;
          int hi = ko >> 4, qd = (ko >> 2) & 3, j4 = ko & 3;
          int nb = dh >> 4, vl16 = dh & 15, e = hi * 4 + j4;
          VF[(size_t)bh * 131072 +
             ((size_t)kt * 256 + nb * 64 + qd * 16 + vl16) * 8 + e] = bv16;
        }
      }
    }
  }
}

// ---- attention: 512 blocks x 8 waves; wave = 32 q-rows x 32-key half ------
// XCD-grouped: bid&7 picks bh group (4 bh per XCD -> 2MB KV in each L2).
// Waves (qw,0)/(qw,1) split the 64-key tile; elementwise same-lane pair
// reduction of ctx/ls at the end.
__global__ __launch_bounds__(512, 4) void attn_kernel(
    const short* __restrict__ Q, const short* __restrict__ KF,
    const short* __restrict__ VF, const uint* __restrict__ bmT,
    short* __restrict__ ctx_out) {
  // dbuf 2 x (K 8KB | V 8KB) = 32KB, + 4KB pad for the final pair-reduce
  __shared__ short lds[18432];
  const int tid = threadIdx.x;           // [0,512)
  const int lane = tid & 63;
  const int wave = tid >> 6;             // [0,8)
  const int qw = wave >> 1;              // [0,4): which 32-q subtile
  const int kbt = wave & 1;              // which 32-key half this wave owns
  const int l16 = lane & 15;
  const int quad = lane >> 4;
  const int xcd = blockIdx.x & 7;        // hw XCD round-robin digit
  const int slot = blockIdx.x >> 3;      // [0,64)
  const int bh = xcd * 4 + (slot >> 4);  // 32 bh, grouped 4-per-XCD
  const int qt128 = slot & 15;
  const int b = bh >> 4;
  const int h = bh & 15;
  const int qbase = qt128 * 128 + qw * 32;

  const short* Qh = Q + (size_t)bh * S_ * DH_;
  const short* KFb = KF + (size_t)bh * 131072;
  const short* VFb = VF + (size_t)bh * 131072;
  const uint* bmb = bmT + (size_t)b * (S_ / 32) * S_;

  s16x8 qf[2][2];
#pragma unroll
  for (int qg = 0; qg < 2; ++qg)
#pragma unroll
    for (int kf = 0; kf < 2; ++kf)
      qf[qg][kf] = *(const s16x8*)(Qh + (size_t)(qbase + qg * 16 + l16) * DH_ +
                                   kf * 32 + quad * 8);

  f32x4 ctx[2][4];
#pragma unroll
  for (int qg = 0; qg < 2; ++qg)
#pragma unroll
    for (int nb = 0; nb < 4; ++nb) ctx[qg][nb] = (f32x4){0.f, 0.f, 0.f, 0.f};
  float ls[2] = {0.f, 0.f};

  // prologue: stage tile 0 into buffer 0 (512 thr x 2 async16 = 16KB)
  async16(KFb + tid * 8, lds + tid * 8);
  async16(VFb + tid * 8, lds + 4096 + tid * 8);
  uint w0 = bmb[(size_t)kbt * S_ + qbase + l16];
  uint w1 = bmb[(size_t)kbt * S_ + qbase + 16 + l16];
  __syncthreads();  // buffer 0 ready

  for (int kt2 = 0; kt2 < S_ / 64; ++kt2) {
    // issue next tile's stage + mask prefetch before computing current tile
    uint wn0 = 0, wn1 = 0;
    if (kt2 < S_ / 64 - 1) {
      const int st = ((kt2 & 1) ^ 1) << 13;  // other buffer, in shorts
      const short* kg = KFb + (size_t)(kt2 + 1) * 4096;
      const short* vg = VFb + (size_t)(kt2 + 1) * 4096;
      async16(kg + tid * 8, lds + st + tid * 8);
      async16(vg + tid * 8, lds + st + 4096 + tid * 8);
      wn0 = bmb[(size_t)(2 * (kt2 + 1) + kbt) * S_ + qbase + l16];
      wn1 = bmb[(size_t)(2 * (kt2 + 1) + kbt) * S_ + qbase + 16 + l16];
    }
    const short* kls = lds + ((kt2 & 1) << 13);
    const short* vls = kls + 4096;

    // this wave's fixed 32-key half: K 32x64 = 4 ds_read_b128
    s16x8 ka[2][2];
#pragma unroll
    for (int kb = 0; kb < 2; ++kb)
#pragma unroll
      for (int kf = 0; kf < 2; ++kf)
        ka[kb][kf] =
            *(const s16x8*)(kls + kbt * 2048 + ((kb * 2 + kf) * 64 + lane) * 8);

    // scores^T per q-group: C row = key(quad*4+r), col = q(l16)
    s16x8 pa[2];
    const uint wsh[2] = {w0 >> (quad * 4), w1 >> (quad * 4)};
#pragma unroll
    for (int qg = 0; qg < 2; ++qg) {
      f32x4 sc[2];
#pragma unroll
      for (int kb = 0; kb < 2; ++kb) {
        f32x4 t = mfma_bf16(ka[kb][0], qf[qg][0], (f32x4){0.f, 0.f, 0.f, 0.f});
        sc[kb] = mfma_bf16(ka[kb][1], qf[qg][1], t);
      }
      float sum = 0.f;
#pragma unroll
      for (int kb = 0; kb < 2; ++kb)
#pragma unroll
        for (int r = 0; r < 4; ++r) {
          int bit = (wsh[qg] >> (kb * 16 + r)) & 1;
          float p = bit ? 0.f : __builtin_amdgcn_exp2f(sc[kb][r]);
          sum += p;
          pa[qg][kb * 4 + r] = f2bf_rn(p);
        }
      ls[qg] += sum;
    }

    // PV: V reads shared across both q-groups
#pragma unroll
    for (int nb = 0; nb < 4; ++nb) {
      s16x8 vb = *(const s16x8*)(vls + kbt * 2048 + (nb * 64 + lane) * 8);
#pragma unroll
      for (int qg = 0; qg < 2; ++qg)
        ctx[qg][nb] = mfma_bf16(pa[qg], vb, ctx[qg][nb]);
    }
    __syncthreads();  // next buffer staged + current reads done
    w0 = wn0;
    w1 = wn1;
  }

  // ---- cross-wave key-half reduction (elementwise, same lane) ----
  float* fl = (float*)lds;
  const int foff = qw * 2176;  // 2048 ctx + 128 ls floats per qw
  if (kbt) {
#pragma unroll
    for (int qg = 0; qg < 2; ++qg) {
#pragma unroll
      for (int nb = 0; nb < 4; ++nb)
#pragma unroll
        for (int r = 0; r < 4; ++r)
          fl[foff + ((qg * 4 + nb) * 4 + r) * 64 + lane] = ctx[qg][nb][r];
      fl[foff + 2048 + qg * 64 + lane] = ls[qg];
    }
  }
  __syncthreads();
  if (!kbt) {
#pragma unroll
    for (int qg = 0; qg < 2; ++qg) {
#pragma unroll
      for (int nb = 0; nb < 4; ++nb)
#pragma unroll
        for (int r = 0; r < 4; ++r)
          ctx[qg][nb][r] += fl[foff + ((qg * 4 + nb) * 4 + r) * 64 + lane];
      ls[qg] += fl[foff + 2048 + qg * 64 + lane];
      ls[qg] += __shfl_xor(ls[qg], 16);
      ls[qg] += __shfl_xor(ls[qg], 32);
    }

    // epilogue: ctx C-layout row = q(quad*4+r), col = dh(l16)
#pragma unroll
    for (int qg = 0; qg < 2; ++qg)
#pragma unroll
      for (int r = 0; r < 4; ++r) {
        float lr = __shfl(ls[qg], quad * 4 + r);
        float inv = 1.f / lr;
        int srow = qbase + qg * 16 + quad * 4 + r;
#pragma unroll
        for (int nb = 0; nb < 4; ++nb) {
          int col = h * DH_ + nb * 16 + l16;
          ctx_out[(size_t)(b * S_ + srow) * D_ + col] = f2bf(ctx[qg][nb][r] * inv);
        }
      }
  }
}

// ---- final GEMM, staged: out[4096,1024] fp32 = ctx_bf16 @ Wo_bf16^T + bo ---
__global__ __launch_bounds__(256) void gemm_final_kernel(
    const short* __restrict__ A, const short* __restrict__ Bt,
    const float* __restrict__ bias, float* __restrict__ out) {
  __shared__ short lds[8192];
  const int tid = threadIdx.x;
  const int lane = tid & 63;
  const int wave = tid >> 6;
  const int l16 = lane & 15;
  const int quad = lane >> 4;
  const int m0 = blockIdx.x * 128;
  const int n0 = blockIdx.y * 128;
  const int g = tid >> 6, c = tid & 63;
  const int r15 = c & 15, qd = c >> 4;

  f32x4 acc[4][4];
#pragma unroll
  for (int i = 0; i < 4; ++i)
#pragma unroll
    for (int j = 0; j < 4; ++j) acc[i][j] = (f32x4){0.f, 0.f, 0.f, 0.f};

  for (int k0 = 0; k0 < 1024; k0 += 32) {
    async16(A + (size_t)(m0 + g * 16 + r15) * 1024 + k0 + qd * 8, lds + tid * 8);
    async16(A + (size_t)(m0 + (g + 4) * 16 + r15) * 1024 + k0 + qd * 8,
            lds + 2048 + tid * 8);
    async16(Bt + (size_t)(n0 + g * 16 + r15) * 1024 + k0 + qd * 8,
            lds + 4096 + tid * 8);
    async16(Bt + (size_t)(n0 + (g + 4) * 16 + r15) * 1024 + k0 + qd * 8,
            lds + 6144 + tid * 8);
    __syncthreads();
    s16x8 a[4], b[4];
#pragma unroll
    for (int i = 0; i < 4; ++i)
      a[i] = *(const s16x8*)(lds + (((wave >> 1) * 4 + i) * 64 + lane) * 8);
#pragma unroll
    for (int j = 0; j < 4; ++j)
      b[j] = *(const s16x8*)(lds + 4096 + (((wave & 1) * 4 + j) * 64 + lane) * 8);
#pragma unroll
    for (int i = 0; i < 4; ++i)
#pragma unroll
      for (int j = 0; j < 4; ++j) acc[i][j] = mfma_bf16(a[i], b[j], acc[i][j]);
    __syncthreads();
  }

  const int mw = m0 + (wave >> 1) * 64;
  const int nw = n0 + (wave & 1) * 64;
#pragma unroll
  for (int i = 0; i < 4; ++i)
#pragma unroll
    for (int j = 0; j < 4; ++j)
#pragma unroll
      for (int r = 0; r < 4; ++r) {
        int m = mw + i * 16 + quad * 4 + r;
        int n = nw + j * 16 + l16;
        out[(size_t)m * 1024 + n] = acc[i][j][r] + bias[n];
      }
}

extern "C" void kernel_launch(void* const* d_in, const int* in_sizes, int n_in,
                              void* d_out, int out_size, void* d_ws,
                              size_t ws_size, hipStream_t stream) {
  const float* query = (const float*)d_in[0];
  const void* mask = d_in[1];
  const float* Wq = (const float*)d_in[2];
  const float* bq = (const float*)d_in[3];
  const float* Wk = (const float*)d_in[4];
  const float* bk = (const float*)d_in[5];
  const float* Wv = (const float*)d_in[6];
  const float* bv = (const float*)d_in[7];
  const float* Wo = (const float*)d_in[8];
  const float* bo = (const float*)d_in[9];

  const size_t NE = (size_t)B_ * S_ * D_;  // 4194304
  short* ws_s = (short*)d_ws;
  short* q_ws = ws_s;             // [B,H,S,DH] bf16 row-major (8 MB)
  short* KF = ws_s + NE;          // K fragment-order (8 MB)
  short* VF = ws_s + 2 * NE;      // V fragment-order, PV-permuted (8 MB)
  short* ctx_ws = ws_s + 3 * NE;  // [B,S,D] bf16 row-major (8 MB)
  short* wo_bf = ws_s;            // Wo bf16 (2 MB) -- aliases q_ws, written
                                  // only after attn (q_ws dead then)
  // scratch inside d_out (all dead before the final GEMM runs):
  short* qbf = (short*)d_out;          // [0:8M)  query bf16, fragment order
  short* wqkv = qbf + NE;              // [8:14M) Wq|Wk|Wv bf16, fragment order
  uint* bmT = (uint*)(wqkv + 3145728); // [14:15M) bitmask
  int* flag = (int*)(bmT + 262144);

  detect_mask_kernel<<<1, 64, 0, stream>>>((const uint*)mask, flag);
  build_bitmask_kernel<<<1024, 256, 0, stream>>>(mask, flag, bmT);
  convert_kernel<<<3584, 256, 0, stream>>>(query, Wq, Wk, Wv, qbf, wqkv);

  gemm_qkv_kernel<<<dim3(32, 24), 256, 0, stream>>>(qbf, wqkv, bq, bk, bv,
                                                    q_ws, KF, VF);

  attn_kernel<<<512, 512, 0, stream>>>(q_ws, KF, VF, bmT, ctx_ws);

  convert_wo_kernel<<<512, 256, 0, stream>>>(Wo, wo_bf);

  gemm_final_kernel<<<dim3(32, 8), 256, 0, stream>>>(ctx_ws, wo_bf, bo,
                                                     (float*)d_out);
}